// Round 4
// baseline (318.462 us; speedup 1.0000x reference)
//
#include <hip/hip_runtime.h>
#include <hip/hip_bf16.h>

typedef __bf16 bf16_t;
typedef __bf16 bf16x8 __attribute__((ext_vector_type(8)));
typedef float  f32x4  __attribute__((ext_vector_type(4)));

#define D_DIM 768
#define S_DIM 2048
#define B_DIM 8
#define M_TOT (B_DIM * S_DIM)   // 16384
#define BK 64                   // K-tile; 12 iters over D=768

// async global->LDS, 16B/lane. LDS dest is wave-uniform base + lane*16B;
// the GLOBAL address is per-lane, which lets us bake the XOR swizzle into
// the load side. LDS chunk layout: global chunk c of row r lives at slot
// c^(r&7), making the fragment ds_read_b128 bank-balanced (2 lanes/bank).
#define GLOAD_LDS16(g, l) __builtin_amdgcn_global_load_lds( \
    (const __attribute__((address_space(1))) unsigned int*)(g), \
    (__attribute__((address_space(3))) unsigned int*)(l), 16, 0, 0)

// ---------------- Kernel B: weight transpose + bf16 cast ----------------
__global__ __launch_bounds__(256)
void transpose_weights(const float* __restrict__ Wq, const float* __restrict__ Wk,
                       bf16_t* __restrict__ Wqt, bf16_t* __restrict__ Wkt) {
    __shared__ float tile[32][33];
    const float* W  = blockIdx.z ? Wk  : Wq;
    bf16_t*      Wt = blockIdx.z ? Wkt : Wqt;
    int tx = threadIdx.x & 31, ty = threadIdx.x >> 5;   // 32 x 8
    int bx = blockIdx.x, by = blockIdx.y;
#pragma unroll
    for (int i = 0; i < 4; i++) {
        int k = bx * 32 + ty + i * 8;
        int n = by * 32 + tx;
        tile[ty + i * 8][tx] = W[k * D_DIM + n];
    }
    __syncthreads();
#pragma unroll
    for (int i = 0; i < 4; i++) {
        int n = by * 32 + ty + i * 8;
        int k = bx * 32 + tx;
        Wt[n * D_DIM + k] = (bf16_t)tile[tx][ty + i * 8];
    }
}

// ---------------- Kernel C: projection GEMM (cast fused into A staging) ----
// Out[m][n] = bf16( sum_k X[m][k] * Wt[n][k] + bias[n] ); z picks q/k.
__global__ __launch_bounds__(256)
void proj_gemm(const float* __restrict__ x1, const float* __restrict__ x2,
               const bf16_t* __restrict__ Wqt, const bf16_t* __restrict__ Wkt,
               const float* __restrict__ bq, const float* __restrict__ bk,
               bf16_t* __restrict__ qb, bf16_t* __restrict__ kb) {
    __shared__ bf16_t lds[2][128 * BK];   // [0]=A, [1]=B ; 32 KB total

    const float*  X    = blockIdx.z ? x2  : x1;
    const bf16_t* Wt   = blockIdx.z ? Wkt : Wqt;
    const float*  bias = blockIdx.z ? bk  : bq;
    bf16_t*       Out  = blockIdx.z ? kb  : qb;

    const int m0 = blockIdx.y * 128;
    const int n0 = blockIdx.x * 128;
    const int tid  = threadIdx.x;
    const int lane = tid & 63;
    const int wid  = tid >> 6;
    const int wm   = wid & 1;
    const int wn   = wid >> 1;
    const int lrow = lane & 15;
    const int quad = lane >> 4;

    f32x4 acc[4][4];
#pragma unroll
    for (int i = 0; i < 4; i++)
#pragma unroll
        for (int j = 0; j < 4; j++) acc[i][j] = (f32x4){0.f, 0.f, 0.f, 0.f};

    // A staging (manual fp32->bf16): thread t -> row t>>1, chunks (t&1)*4..+3
    const int arow  = tid >> 1;
    const int ahalf = (tid & 1) * 4;
    const float* agp = X + (size_t)(m0 + arow) * D_DIM + ahalf * 8;
    bf16_t* alds = &lds[0][arow * BK];

    // B staging via global_load_lds: wave wid covers chunk-linear [wid*256, +256)
    const bf16_t* bgp = Wt + (size_t)n0 * D_DIM;

    for (int k0 = 0; k0 < D_DIM; k0 += BK) {
#pragma unroll
        for (int i = 0; i < 4; i++) {
            int linear = wid * 256 + i * 64 + lane;
            int row  = linear >> 3;
            int c    = (linear & 7) ^ (row & 7);
            GLOAD_LDS16(bgp + (size_t)row * D_DIM + k0 + c * 8,
                        &lds[1][(size_t)(wid * 256 + i * 64) * 8]);
        }
#pragma unroll
        for (int c = 0; c < 4; c++) {
            float4 u = *(const float4*)(agp + k0 + c * 8);
            float4 v = *(const float4*)(agp + k0 + c * 8 + 4);
            bf16x8 r;
            r[0] = (bf16_t)u.x; r[1] = (bf16_t)u.y; r[2] = (bf16_t)u.z; r[3] = (bf16_t)u.w;
            r[4] = (bf16_t)v.x; r[5] = (bf16_t)v.y; r[6] = (bf16_t)v.z; r[7] = (bf16_t)v.w;
            *(bf16x8*)&alds[((ahalf + c) ^ (arow & 7)) * 8] = r;
        }
        __syncthreads();

#pragma unroll
        for (int j = 0; j < 2; j++) {
            bf16x8 af[4], bfr[4];
#pragma unroll
            for (int f = 0; f < 4; f++) {
                int ra = wm * 64 + f * 16 + lrow;
                int rb = wn * 64 + f * 16 + lrow;
                af[f]  = *(const bf16x8*)&lds[0][(ra * 8 + ((j * 4 + quad) ^ (ra & 7))) * 8];
                bfr[f] = *(const bf16x8*)&lds[1][(rb * 8 + ((j * 4 + quad) ^ (rb & 7))) * 8];
            }
#pragma unroll
            for (int fm = 0; fm < 4; fm++)
#pragma unroll
                for (int fn = 0; fn < 4; fn++)
                    acc[fm][fn] = __builtin_amdgcn_mfma_f32_16x16x32_bf16(
                        af[fm], bfr[fn], acc[fm][fn], 0, 0, 0);
        }
        __syncthreads();
    }

    // epilogue: acc -> LDS (bf16 [128][128]) -> coalesced 16B stores
    bf16_t* cbuf = &lds[0][0];   // 32 KB = exactly 128*128 bf16
#pragma unroll
    for (int fn = 0; fn < 4; fn++) {
        int col = wn * 64 + fn * 16 + lrow;
        float bv = bias[n0 + col];
#pragma unroll
        for (int fm = 0; fm < 4; fm++) {
            int rbase = wm * 64 + fm * 16 + quad * 4;
#pragma unroll
            for (int r = 0; r < 4; r++)
                cbuf[(rbase + r) * 128 + col] = (bf16_t)(acc[fm][fn][r] + bv);
        }
    }
    __syncthreads();
    {
        int row = tid >> 1, cb = (tid & 1) * 64;
#pragma unroll
        for (int i = 0; i < 8; i++)
            *(uint4*)(Out + (size_t)(m0 + row) * D_DIM + n0 + cb + i * 8) =
                *(const uint4*)&cbuf[row * 128 + cb + i * 8];
    }
}

// ---------------- Kernel D: qk tile + w=exp(tanh) + column reduce ----------
__global__ __launch_bounds__(256)
void attn_reduce(const bf16_t* __restrict__ Q, const bf16_t* __restrict__ K,
                 float* __restrict__ num, float* __restrict__ den) {
    __shared__ bf16_t lds[2][128 * BK];   // 32 KB

    const int b  = blockIdx.z;
    const int s0 = blockIdx.y * 128;
    const int t0 = blockIdx.x * 128;
    const bf16_t* Qb = Q + (size_t)b * S_DIM * D_DIM;
    const bf16_t* Kb = K + (size_t)b * S_DIM * D_DIM;

    const int tid  = threadIdx.x;
    const int lane = tid & 63;
    const int wid  = tid >> 6;
    const int wm   = wid & 1;
    const int wn   = wid >> 1;
    const int lrow = lane & 15;
    const int quad = lane >> 4;

    f32x4 acc[4][4];
#pragma unroll
    for (int i = 0; i < 4; i++)
#pragma unroll
        for (int j = 0; j < 4; j++) acc[i][j] = (f32x4){0.f, 0.f, 0.f, 0.f};

    for (int k0 = 0; k0 < D_DIM; k0 += BK) {
#pragma unroll
        for (int i = 0; i < 4; i++) {
            int linear = wid * 256 + i * 64 + lane;
            int row  = linear >> 3;
            int c    = (linear & 7) ^ (row & 7);
            GLOAD_LDS16(Qb + (size_t)(s0 + row) * D_DIM + k0 + c * 8,
                        &lds[0][(size_t)(wid * 256 + i * 64) * 8]);
            GLOAD_LDS16(Kb + (size_t)(t0 + row) * D_DIM + k0 + c * 8,
                        &lds[1][(size_t)(wid * 256 + i * 64) * 8]);
        }
        __syncthreads();

#pragma unroll
        for (int j = 0; j < 2; j++) {
            bf16x8 af[4], bfr[4];
#pragma unroll
            for (int f = 0; f < 4; f++) {
                int ra = wm * 64 + f * 16 + lrow;
                int rb = wn * 64 + f * 16 + lrow;
                af[f]  = *(const bf16x8*)&lds[0][(ra * 8 + ((j * 4 + quad) ^ (ra & 7))) * 8];
                bfr[f] = *(const bf16x8*)&lds[1][(rb * 8 + ((j * 4 + quad) ^ (rb & 7))) * 8];
            }
#pragma unroll
            for (int fm = 0; fm < 4; fm++)
#pragma unroll
                for (int fn = 0; fn < 4; fn++)
                    acc[fm][fn] = __builtin_amdgcn_mfma_f32_16x16x32_bf16(
                        af[fm], bfr[fn], acc[fm][fn], 0, 0, 0);
        }
        __syncthreads();
    }

    // w = exp(tanh(qk)); per-column (t) partials over this wave's 64 s-rows
    float sw[4], swv[4];
#pragma unroll
    for (int fn = 0; fn < 4; fn++) { sw[fn] = 0.f; swv[fn] = 0.f; }
#pragma unroll
    for (int fm = 0; fm < 4; fm++)
#pragma unroll
        for (int fn = 0; fn < 4; fn++)
#pragma unroll
            for (int r = 0; r < 4; r++) {
                float v = acc[fm][fn][r];
                float e2 = __expf(2.f * v);           // tanh via exp; saturates to 1
                float t  = 1.f - 2.f / (e2 + 1.f);
                float w  = __expf(t);
                sw[fn]  += w;
                swv[fn] += w * v;
            }
#pragma unroll
    for (int fn = 0; fn < 4; fn++) {
        sw[fn]  += __shfl_xor(sw[fn], 16);  sw[fn]  += __shfl_xor(sw[fn], 32);
        swv[fn] += __shfl_xor(swv[fn], 16); swv[fn] += __shfl_xor(swv[fn], 32);
    }
    // reuse dead LDS for cross-wave reduction.
    // layout: float red[2][2][128] -> index (which*2 + wm)*128 + col
    //   sw  (which=0): floats   0..255
    //   swv (which=1): floats 256..511
    float* red = (float*)&lds[0][0];
    if (quad == 0) {
#pragma unroll
        for (int fn = 0; fn < 4; fn++) {
            red[(0 * 2 + wm) * 128 + wn * 64 + fn * 16 + lrow] = sw[fn];
            red[(1 * 2 + wm) * 128 + wn * 64 + fn * 16 + lrow] = swv[fn];
        }
    }
    __syncthreads();
    if (tid < 128) {
        int t = t0 + tid;
        atomicAdd(&den[b * S_DIM + t], red[  0 + tid] + red[128 + tid]);
        atomicAdd(&num[b * S_DIM + t], red[256 + tid] + red[384 + tid]);   // FIXED (was 512+)
    }
}

// ---------------- Kernel E: finalize ----------------
__global__ __launch_bounds__(256)
void finalize(const float* __restrict__ num, const float* __restrict__ den,
              float* __restrict__ out, int n) {
    int i = blockIdx.x * 256 + threadIdx.x;
    if (i < n) out[i] = num[i] / (den[i] + 1e-7f);
}

extern "C" void kernel_launch(void* const* d_in, const int* in_sizes, int n_in,
                              void* d_out, int out_size, void* d_ws, size_t ws_size,
                              hipStream_t stream) {
    (void)in_sizes; (void)n_in; (void)out_size; (void)ws_size;
    const float* x1 = (const float*)d_in[0];
    const float* x2 = (const float*)d_in[1];
    const float* Wq = (const float*)d_in[2];
    const float* bq = (const float*)d_in[3];
    const float* Wk = (const float*)d_in[4];
    const float* bk = (const float*)d_in[5];
    float* out = (float*)d_out;

    char* ws = (char*)d_ws;
    size_t off = 0;
    bf16_t* qb  = (bf16_t*)(ws + off); off += (size_t)M_TOT * D_DIM * 2;   // 25.2 MB
    bf16_t* kb  = (bf16_t*)(ws + off); off += (size_t)M_TOT * D_DIM * 2;
    bf16_t* Wqt = (bf16_t*)(ws + off); off += (size_t)D_DIM * D_DIM * 2;
    bf16_t* Wkt = (bf16_t*)(ws + off); off += (size_t)D_DIM * D_DIM * 2;
    float*  num = (float*)(ws + off);  off += (size_t)M_TOT * 4;
    float*  den = (float*)(ws + off);  off += (size_t)M_TOT * 4;

    hipMemsetAsync(num, 0, (size_t)M_TOT * 4 * 2, stream);

    transpose_weights<<<dim3(24, 24, 2), 256, 0, stream>>>(Wq, Wk, Wqt, Wkt);
    proj_gemm<<<dim3(6, 128, 2), 256, 0, stream>>>(x1, x2, Wqt, Wkt, bq, bk, qb, kb);
    attn_reduce<<<dim3(16, 16, 8), 256, 0, stream>>>(qb, kb, num, den);
    finalize<<<dim3((M_TOT + 255) / 256), 256, 0, stream>>>(num, den, out, M_TOT);
}

// Round 5
// 286.059 us; speedup vs baseline: 1.1133x; 1.1133x over previous
//
#include <hip/hip_runtime.h>
#include <hip/hip_bf16.h>

typedef __bf16 bf16_t;
typedef __bf16 bf16x8 __attribute__((ext_vector_type(8)));
typedef float  f32x4  __attribute__((ext_vector_type(4)));

#define D_DIM 768
#define S_DIM 2048
#define B_DIM 8
#define M_TOT (B_DIM * S_DIM)   // 16384
#define BK 64                   // K-tile; 12 iters over D=768

// async global->LDS, 16B/lane. LDS dest is wave-uniform base + lane*16B;
// the GLOBAL address is per-lane, letting us bake the XOR swizzle into the
// load side. LDS chunk layout: global chunk c of row r lives at slot c^(r&7),
// making the fragment ds_read_b128 bank-balanced.
#define GLOAD_LDS16(g, l) __builtin_amdgcn_global_load_lds( \
    (const __attribute__((address_space(1))) unsigned int*)(g), \
    (__attribute__((address_space(3))) unsigned int*)(l), 16, 0, 0)

// ---------------- Kernel A: fp32 -> bf16 cast of x1/x2 ----------------
// Pays for itself: halves the bytes proj re-streams 6x over the n-tiles.
__global__ __launch_bounds__(256)
void cast_inputs(const float* __restrict__ x1, const float* __restrict__ x2,
                 bf16_t* __restrict__ o1, bf16_t* __restrict__ o2) {
    const float* x = blockIdx.z ? x2 : x1;
    bf16_t*      o = blockIdx.z ? o2 : o1;
    size_t i = ((size_t)blockIdx.x * 256 + threadIdx.x) * 8;  // grid sized exactly
    float4 a = *(const float4*)(x + i);
    float4 b = *(const float4*)(x + i + 4);
    bf16x8 r;
    r[0] = (bf16_t)a.x; r[1] = (bf16_t)a.y; r[2] = (bf16_t)a.z; r[3] = (bf16_t)a.w;
    r[4] = (bf16_t)b.x; r[5] = (bf16_t)b.y; r[6] = (bf16_t)b.z; r[7] = (bf16_t)b.w;
    *(bf16x8*)(o + i) = r;
}

// ---------------- Kernel B: weight transpose + bf16 cast ----------------
__global__ __launch_bounds__(256)
void transpose_weights(const float* __restrict__ Wq, const float* __restrict__ Wk,
                       bf16_t* __restrict__ Wqt, bf16_t* __restrict__ Wkt) {
    __shared__ float tile[32][33];
    const float* W  = blockIdx.z ? Wk  : Wq;
    bf16_t*      Wt = blockIdx.z ? Wkt : Wqt;
    int tx = threadIdx.x & 31, ty = threadIdx.x >> 5;   // 32 x 8
    int bx = blockIdx.x, by = blockIdx.y;
#pragma unroll
    for (int i = 0; i < 4; i++) {
        int k = bx * 32 + ty + i * 8;
        int n = by * 32 + tx;
        tile[ty + i * 8][tx] = W[k * D_DIM + n];
    }
    __syncthreads();
#pragma unroll
    for (int i = 0; i < 4; i++) {
        int n = by * 32 + ty + i * 8;
        int k = bx * 32 + tx;
        Wt[n * D_DIM + k] = (bf16_t)tile[tx][ty + i * 8];
    }
}

// ---------------- Kernel C: projection GEMM (all-bf16, all-GLOAD staging) ---
// Out[m][n] = bf16( sum_k Xb[m][k] * Wt[n][k] + bias[n] ); z picks q/k.
__global__ __launch_bounds__(256)
void proj_gemm(const bf16_t* __restrict__ x1b, const bf16_t* __restrict__ x2b,
               const bf16_t* __restrict__ Wqt, const bf16_t* __restrict__ Wkt,
               const float* __restrict__ bq, const float* __restrict__ bk,
               bf16_t* __restrict__ qb, bf16_t* __restrict__ kb) {
    __shared__ bf16_t lds[2][128 * BK];   // [0]=A, [1]=B ; 32 KB total

    const bf16_t* X    = blockIdx.z ? x2b : x1b;
    const bf16_t* Wt   = blockIdx.z ? Wkt : Wqt;
    const float*  bias = blockIdx.z ? bk  : bq;
    bf16_t*       Out  = blockIdx.z ? kb  : qb;

    const int m0 = blockIdx.y * 128;
    const int n0 = blockIdx.x * 128;
    const int tid  = threadIdx.x;
    const int lane = tid & 63;
    const int wid  = tid >> 6;
    const int wm   = wid & 1;
    const int wn   = wid >> 1;
    const int lrow = lane & 15;
    const int quad = lane >> 4;

    f32x4 acc[4][4];
#pragma unroll
    for (int i = 0; i < 4; i++)
#pragma unroll
        for (int j = 0; j < 4; j++) acc[i][j] = (f32x4){0.f, 0.f, 0.f, 0.f};

    const bf16_t* ag = X  + (size_t)m0 * D_DIM;
    const bf16_t* bg = Wt + (size_t)n0 * D_DIM;

    for (int k0 = 0; k0 < D_DIM; k0 += BK) {
#pragma unroll
        for (int i = 0; i < 4; i++) {
            int linear = wid * 256 + i * 64 + lane;
            int row  = linear >> 3;
            int c    = (linear & 7) ^ (row & 7);
            GLOAD_LDS16(ag + (size_t)row * D_DIM + k0 + c * 8,
                        &lds[0][(size_t)(wid * 256 + i * 64) * 8]);
            GLOAD_LDS16(bg + (size_t)row * D_DIM + k0 + c * 8,
                        &lds[1][(size_t)(wid * 256 + i * 64) * 8]);
        }
        __syncthreads();

#pragma unroll
        for (int j = 0; j < 2; j++) {
            bf16x8 af[4], bfr[4];
#pragma unroll
            for (int f = 0; f < 4; f++) {
                int ra = wm * 64 + f * 16 + lrow;
                int rb = wn * 64 + f * 16 + lrow;
                af[f]  = *(const bf16x8*)&lds[0][(ra * 8 + ((j * 4 + quad) ^ (ra & 7))) * 8];
                bfr[f] = *(const bf16x8*)&lds[1][(rb * 8 + ((j * 4 + quad) ^ (rb & 7))) * 8];
            }
#pragma unroll
            for (int fm = 0; fm < 4; fm++)
#pragma unroll
                for (int fn = 0; fn < 4; fn++)
                    acc[fm][fn] = __builtin_amdgcn_mfma_f32_16x16x32_bf16(
                        af[fm], bfr[fn], acc[fm][fn], 0, 0, 0);
        }
        __syncthreads();
    }

    // epilogue: acc -> LDS (bf16 [128][128]) -> coalesced 16B stores
    bf16_t* cbuf = &lds[0][0];   // 32 KB = exactly 128*128 bf16
#pragma unroll
    for (int fn = 0; fn < 4; fn++) {
        int col = wn * 64 + fn * 16 + lrow;
        float bv = bias[n0 + col];
#pragma unroll
        for (int fm = 0; fm < 4; fm++) {
            int rbase = wm * 64 + fm * 16 + quad * 4;
#pragma unroll
            for (int r = 0; r < 4; r++)
                cbuf[(rbase + r) * 128 + col] = (bf16_t)(acc[fm][fn][r] + bv);
        }
    }
    __syncthreads();
    {
        int row = tid >> 1, cb = (tid & 1) * 64;
#pragma unroll
        for (int i = 0; i < 8; i++)
            *(uint4*)(Out + (size_t)(m0 + row) * D_DIM + n0 + cb + i * 8) =
                *(const uint4*)&cbuf[row * 128 + cb + i * 8];
    }
}

// ---------------- Kernel D: qk tile + w=exp(tanh) + column reduce ----------
__global__ __launch_bounds__(256)
void attn_reduce(const bf16_t* __restrict__ Q, const bf16_t* __restrict__ K,
                 float* __restrict__ num, float* __restrict__ den) {
    __shared__ bf16_t lds[2][128 * BK];   // 32 KB

    const int b  = blockIdx.z;
    const int s0 = blockIdx.y * 128;
    const int t0 = blockIdx.x * 128;
    const bf16_t* Qb = Q + (size_t)b * S_DIM * D_DIM;
    const bf16_t* Kb = K + (size_t)b * S_DIM * D_DIM;

    const int tid  = threadIdx.x;
    const int lane = tid & 63;
    const int wid  = tid >> 6;
    const int wm   = wid & 1;
    const int wn   = wid >> 1;
    const int lrow = lane & 15;
    const int quad = lane >> 4;

    f32x4 acc[4][4];
#pragma unroll
    for (int i = 0; i < 4; i++)
#pragma unroll
        for (int j = 0; j < 4; j++) acc[i][j] = (f32x4){0.f, 0.f, 0.f, 0.f};

    for (int k0 = 0; k0 < D_DIM; k0 += BK) {
#pragma unroll
        for (int i = 0; i < 4; i++) {
            int linear = wid * 256 + i * 64 + lane;
            int row  = linear >> 3;
            int c    = (linear & 7) ^ (row & 7);
            GLOAD_LDS16(Qb + (size_t)(s0 + row) * D_DIM + k0 + c * 8,
                        &lds[0][(size_t)(wid * 256 + i * 64) * 8]);
            GLOAD_LDS16(Kb + (size_t)(t0 + row) * D_DIM + k0 + c * 8,
                        &lds[1][(size_t)(wid * 256 + i * 64) * 8]);
        }
        __syncthreads();

#pragma unroll
        for (int j = 0; j < 2; j++) {
            bf16x8 af[4], bfr[4];
#pragma unroll
            for (int f = 0; f < 4; f++) {
                int ra = wm * 64 + f * 16 + lrow;
                int rb = wn * 64 + f * 16 + lrow;
                af[f]  = *(const bf16x8*)&lds[0][(ra * 8 + ((j * 4 + quad) ^ (ra & 7))) * 8];
                bfr[f] = *(const bf16x8*)&lds[1][(rb * 8 + ((j * 4 + quad) ^ (rb & 7))) * 8];
            }
#pragma unroll
            for (int fm = 0; fm < 4; fm++)
#pragma unroll
                for (int fn = 0; fn < 4; fn++)
                    acc[fm][fn] = __builtin_amdgcn_mfma_f32_16x16x32_bf16(
                        af[fm], bfr[fn], acc[fm][fn], 0, 0, 0);
        }
        __syncthreads();
    }

    // w = exp(tanh(qk)); per-column (t) partials over this wave's 64 s-rows
    float sw[4], swv[4];
#pragma unroll
    for (int fn = 0; fn < 4; fn++) { sw[fn] = 0.f; swv[fn] = 0.f; }
#pragma unroll
    for (int fm = 0; fm < 4; fm++)
#pragma unroll
        for (int fn = 0; fn < 4; fn++)
#pragma unroll
            for (int r = 0; r < 4; r++) {
                float v = acc[fm][fn][r];
                float e2 = __expf(2.f * v);           // tanh via exp; saturates to 1
                float t  = 1.f - 2.f / (e2 + 1.f);
                float w  = __expf(t);
                sw[fn]  += w;
                swv[fn] += w * v;
            }
#pragma unroll
    for (int fn = 0; fn < 4; fn++) {
        sw[fn]  += __shfl_xor(sw[fn], 16);  sw[fn]  += __shfl_xor(sw[fn], 32);
        swv[fn] += __shfl_xor(swv[fn], 16); swv[fn] += __shfl_xor(swv[fn], 32);
    }
    // reuse dead LDS: float red[2][2][128] -> (which*2 + wm)*128 + col
    float* red = (float*)&lds[0][0];
    if (quad == 0) {
#pragma unroll
        for (int fn = 0; fn < 4; fn++) {
            red[(0 * 2 + wm) * 128 + wn * 64 + fn * 16 + lrow] = sw[fn];
            red[(1 * 2 + wm) * 128 + wn * 64 + fn * 16 + lrow] = swv[fn];
        }
    }
    __syncthreads();
    if (tid < 128) {
        int t = t0 + tid;
        atomicAdd(&den[b * S_DIM + t], red[  0 + tid] + red[128 + tid]);
        atomicAdd(&num[b * S_DIM + t], red[256 + tid] + red[384 + tid]);
    }
}

// ---------------- Kernel E: finalize ----------------
__global__ __launch_bounds__(256)
void finalize(const float* __restrict__ num, const float* __restrict__ den,
              float* __restrict__ out, int n) {
    int i = blockIdx.x * 256 + threadIdx.x;
    if (i < n) out[i] = num[i] / (den[i] + 1e-7f);
}

extern "C" void kernel_launch(void* const* d_in, const int* in_sizes, int n_in,
                              void* d_out, int out_size, void* d_ws, size_t ws_size,
                              hipStream_t stream) {
    (void)in_sizes; (void)n_in; (void)out_size; (void)ws_size;
    const float* x1 = (const float*)d_in[0];
    const float* x2 = (const float*)d_in[1];
    const float* Wq = (const float*)d_in[2];
    const float* bq = (const float*)d_in[3];
    const float* Wk = (const float*)d_in[4];
    const float* bk = (const float*)d_in[5];
    float* out = (float*)d_out;

    char* ws = (char*)d_ws;
    size_t off = 0;
    bf16_t* qb  = (bf16_t*)(ws + off); off += (size_t)M_TOT * D_DIM * 2;   // 25.2 MB
    bf16_t* kb  = (bf16_t*)(ws + off); off += (size_t)M_TOT * D_DIM * 2;
    bf16_t* x1b = (bf16_t*)(ws + off); off += (size_t)M_TOT * D_DIM * 2;
    bf16_t* x2b = (bf16_t*)(ws + off); off += (size_t)M_TOT * D_DIM * 2;
    bf16_t* Wqt = (bf16_t*)(ws + off); off += (size_t)D_DIM * D_DIM * 2;
    bf16_t* Wkt = (bf16_t*)(ws + off); off += (size_t)D_DIM * D_DIM * 2;
    float*  num = (float*)(ws + off);  off += (size_t)M_TOT * 4;
    float*  den = (float*)(ws + off);  off += (size_t)M_TOT * 4;

    hipMemsetAsync(num, 0, (size_t)M_TOT * 4 * 2, stream);

    cast_inputs<<<dim3(6144, 1, 2), 256, 0, stream>>>(x1, x2, x1b, x2b);
    transpose_weights<<<dim3(24, 24, 2), 256, 0, stream>>>(Wq, Wk, Wqt, Wkt);
    proj_gemm<<<dim3(6, 128, 2), 256, 0, stream>>>(x1b, x2b, Wqt, Wkt, bq, bk, qb, kb);
    attn_reduce<<<dim3(16, 16, 8), 256, 0, stream>>>(qb, kb, num, den);
    finalize<<<dim3((M_TOT + 255) / 256), 256, 0, stream>>>(num, den, out, M_TOT);
}